// Round 5
// baseline (415.839 us; speedup 1.0000x reference)
//
#include <hip/hip_runtime.h>
#include <hip/hip_bf16.h>

// Graph mean aggregation via coarse dst-bucketing.
//   bucket = dst >> SHIFT  (NPB=128 nodes per bucket)
//   1) hist:         LDS histogram of buckets -> global bucket_cnt
//   2) scan_bins:    exclusive scan over nb bins (single block)
//   3) pack_scatter: 64 big blocks; per-(block,bin) chunk reservation; packed
//                    (local_dst<<17 | src) written in ~128B single-owner chunks
//   4) aggregate:    SPLIT=4 blocks per bucket, each owns a 32-NODE RANGE:
//                    scans whole bucket segment (streamed), filters by ld,
//                    8-deep shfl-batched h4 gathers (MLP), LDS atomics into a
//                    private 32x33 slab, direct coalesced store with fused
//                    mean divide. No global atomics, no merge, no finalize.

#define D_FEAT 32
#define NPB 128
#define SHIFT 7
#define SPLIT 4
#define NR (NPB / SPLIT)      // 32 nodes per aggregate block
#define PACK_GRID 64
#define PACK_BLOCK 1024

__global__ void zero_i32_kernel(int* __restrict__ p, int n) {
    for (int i = blockIdx.x * blockDim.x + threadIdx.x; i < n;
         i += gridDim.x * blockDim.x) p[i] = 0;
}

__global__ void hist_kernel(const int* __restrict__ dst, int n_edges,
                            int* __restrict__ bucket_cnt, int nb) {
    extern __shared__ int lbin[];
    for (int i = threadIdx.x; i < nb; i += blockDim.x) lbin[i] = 0;
    __syncthreads();
    for (int i = blockIdx.x * blockDim.x + threadIdx.x; i < n_edges;
         i += gridDim.x * blockDim.x)
        atomicAdd(&lbin[dst[i] >> SHIFT], 1);
    __syncthreads();
    for (int i = threadIdx.x; i < nb; i += blockDim.x)
        if (lbin[i]) atomicAdd(&bucket_cnt[i], lbin[i]);
}

__global__ void scan_bins_kernel(const int* __restrict__ cnt,
                                 int* __restrict__ off,
                                 int* __restrict__ cur, int nb) {
    __shared__ int tmp[1024];
    int t = threadIdx.x;
    int orig = (t < nb) ? cnt[t] : 0;
    int v = orig;
    for (int o = 1; o < 1024; o <<= 1) {
        tmp[t] = v;
        __syncthreads();
        if (t >= o) v += tmp[t - o];
        __syncthreads();
    }
    if (t < nb) {
        off[t] = v - orig;
        cur[t] = v - orig;
        if (t == nb - 1) off[nb] = v;
    }
}

__global__ __launch_bounds__(PACK_BLOCK) void pack_scatter_kernel(
        const int* __restrict__ src, const int* __restrict__ dst, int n_edges,
        int* __restrict__ bucket_cur, unsigned int* __restrict__ packed,
        int nb, int epb) {
    extern __shared__ int sh[];     // 2*nb ints
    int* lcnt = sh;
    int* lcur = sh + nb;
    int lo = blockIdx.x * epb;
    int hi = min(lo + epb, n_edges);
    for (int i = threadIdx.x; i < nb; i += blockDim.x) lcnt[i] = 0;
    __syncthreads();
    for (int i = lo + threadIdx.x; i < hi; i += blockDim.x)
        atomicAdd(&lcnt[dst[i] >> SHIFT], 1);
    __syncthreads();
    for (int i = threadIdx.x; i < nb; i += blockDim.x) {
        int c = lcnt[i];
        lcur[i] = c ? atomicAdd(&bucket_cur[i], c) : 0;
    }
    __syncthreads();
    for (int i = lo + threadIdx.x; i < hi; i += blockDim.x) {
        int dd = dst[i];
        int b = dd >> SHIFT;
        int pos = atomicAdd(&lcur[b], 1);
        packed[pos] = ((unsigned)(dd & (NPB - 1)) << 17) | (unsigned)src[i];
    }
}

__global__ __launch_bounds__(256) void aggregate_kernel(
        const float4* __restrict__ h4, const unsigned int* __restrict__ packed,
        const int* __restrict__ off, float* __restrict__ out, int n_nodes) {
    __shared__ float acc[NR * 33];   // padded
    __shared__ int degi[NR];
    int b = blockIdx.x >> 2;         // bucket (SPLIT==4)
    int c = blockIdx.x & 3;          // node-range split
    for (int i = threadIdx.x; i < NR * 33; i += 256) acc[i] = 0.0f;
    if (threadIdx.x < NR) degi[threadIdx.x] = 0;
    __syncthreads();

    int beg = off[b], end = off[b + 1];
    int lane    = threadIdx.x & 63;
    int q       = lane & 7;          // float4 quarter-row
    int grpbase = lane & 56;         // first lane of this 8-lane group
    int lo_ld   = c * NR;

    for (int tile = beg; tile < end; tile += 256) {
        int idx = tile + threadIdx.x;
        unsigned int myp = (idx < end) ? packed[idx] : 0xFFFFFFFFu;
        #pragma unroll
        for (int k = 0; k < 8; ++k) {
            unsigned int p = __shfl(myp, grpbase + k, 64);
            int ld = (int)(p >> 17);
            unsigned int r = (unsigned int)(ld - lo_ld);
            if (r < NR) {               // this split owns the node (also
                                        // rejects the 0xFFFFFFFF sentinel)
                int s = (int)(p & 0x1FFFFu);
                float4 v = h4[(size_t)s * 8 + q];
                int a = (int)r * 33 + q * 4;
                atomicAdd(&acc[a + 0], v.x);
                atomicAdd(&acc[a + 1], v.y);
                atomicAdd(&acc[a + 2], v.z);
                atomicAdd(&acc[a + 3], v.w);
                if (q == 0) atomicAdd(&degi[r], 1);
            }
        }
    }
    __syncthreads();

    int nodebase = b * NPB + c * NR;
    size_t obase = (size_t)nodebase * D_FEAT;
    for (int i = threadIdx.x; i < NR * D_FEAT; i += 256) {
        int ln = i >> 5, d = i & 31;
        if (nodebase + ln < n_nodes)
            out[obase + i] = acc[ln * 33 + d] / fmaxf((float)degi[ln], 1.0f);
    }
}

// ---------------- fallback (round-1 atomic path) if ws too small -------------
__global__ void zero_init_fb(float* __restrict__ out, int out_n,
                             float* __restrict__ deg, int n_nodes) {
    int total = out_n + n_nodes;
    for (int i = blockIdx.x * blockDim.x + threadIdx.x; i < total;
         i += gridDim.x * blockDim.x) {
        if (i < out_n) out[i] = 0.0f;
        else deg[i - out_n] = 0.0f;
    }
}
__global__ void scatter_fb(const float* __restrict__ h,
                           const int* __restrict__ src,
                           const int* __restrict__ dst,
                           float* __restrict__ out,
                           float* __restrict__ deg, int n_edges) {
    long long tid = (long long)blockIdx.x * blockDim.x + threadIdx.x;
    long long total = (long long)n_edges * D_FEAT;
    if (tid >= total) return;
    int e = (int)(tid >> 5);
    int d = (int)(tid & 31);
    float v = h[(long long)src[e] * D_FEAT + d];
    atomicAdd(&out[(long long)dst[e] * D_FEAT + d], v);
    if (d == 0) atomicAdd(&deg[dst[e]], 1.0f);
}
__global__ void finalize_fb(float* __restrict__ out,
                            const float* __restrict__ deg, int n_nodes) {
    int total = n_nodes * D_FEAT;
    for (int i = blockIdx.x * blockDim.x + threadIdx.x; i < total;
         i += gridDim.x * blockDim.x)
        out[i] = out[i] / fmaxf(deg[i >> 5], 1.0f);
}
// -----------------------------------------------------------------------------

extern "C" void kernel_launch(void* const* d_in, const int* in_sizes, int n_in,
                              void* d_out, int out_size, void* d_ws, size_t ws_size,
                              hipStream_t stream) {
    const float* h = (const float*)d_in[0];
    const int* src = (const int*)d_in[1];
    const int* dst = (const int*)d_in[2];
    float* out = (float*)d_out;

    int n_nodes = in_sizes[0] / D_FEAT;
    int n_edges = in_sizes[1];
    int nb = (n_nodes + NPB - 1) >> SHIFT;

    size_t need = ((size_t)3 * nb + 1 + (size_t)n_edges) * sizeof(int);
    if (ws_size < need || nb > 1024 || n_nodes > 131072) {
        float* deg = (float*)d_ws;
        int total0 = n_nodes * D_FEAT + n_nodes;
        zero_init_fb<<<min((total0 + 255) / 256, 2048), 256, 0, stream>>>(
            out, n_nodes * D_FEAT, deg, n_nodes);
        long long total = (long long)n_edges * D_FEAT;
        scatter_fb<<<(int)((total + 255) / 256), 256, 0, stream>>>(
            h, src, dst, out, deg, n_edges);
        finalize_fb<<<min((n_nodes * D_FEAT + 255) / 256, 2048), 256, 0,
                      stream>>>(out, deg, n_nodes);
        return;
    }

    int* wsI        = (int*)d_ws;
    int* bucket_cnt = wsI;                   // nb
    int* bucket_off = bucket_cnt + nb;       // nb + 1
    int* bucket_cur = bucket_off + nb + 1;   // nb
    unsigned int* packed = (unsigned int*)(bucket_cur + nb);  // n_edges

    zero_i32_kernel<<<4, 256, 0, stream>>>(bucket_cnt, nb);
    hist_kernel<<<256, 256, nb * sizeof(int), stream>>>(dst, n_edges, bucket_cnt, nb);
    scan_bins_kernel<<<1, 1024, 0, stream>>>(bucket_cnt, bucket_off, bucket_cur, nb);
    int epb = (n_edges + PACK_GRID - 1) / PACK_GRID;
    pack_scatter_kernel<<<PACK_GRID, PACK_BLOCK, 2 * nb * sizeof(int), stream>>>(
        src, dst, n_edges, bucket_cur, packed, nb, epb);
    aggregate_kernel<<<nb * SPLIT, 256, 0, stream>>>(
        (const float4*)h, packed, bucket_off, out, n_nodes);
}